// Round 4
// baseline (238.770 us; speedup 1.0000x reference)
//
#include <hip/hip_runtime.h>

// PositionEncoder: out[b][s][0:512] = x[b][s][:], out[b][s][512:517] = enc(s)
// B=64, S=1024, D=512, H=W=32.  enc[k] = ((x>>(4-k))&1) & !((y>>(4-k))&1),
// y=s>>5, x=s&31  (verified absmax=0.0 R1-R3, R5, R6).
//
// Round-7: wave-autonomous global_load_lds staging, zero barriers.
// R5/R6 post-mortem: register-realign structures lose to LDS staging (R3)
// because of per-f4 overhead + divergent boundary paths with extra global
// loads. So keep R3's skeleton and remove R3's own costs instead:
//  - stage 1 via __builtin_amdgcn_global_load_lds width=16 (HBM->LDS direct):
//    kills the 16 8-way-conflicted ds_write_b32 per thread, the VGPR
//    round-trip, and the staging address VALU.
//  - each WAVE owns a private 8 KB image of 4 x-rows (4 rows = 517 out-f4s
//    exactly, group start 16B-aligned) -> no __syncthreads at all; the wave
//    waits on its own vmcnt(0) and proceeds. Block-wide drain bubble gone.
//  - stage 2: realigned ds_read_b32 x4 from the image (8-way conflict, same
//    magnitude R3 paid on writes; LDS pipe ~34% of memory time -> hidden);
//    boundary f4s (8/group) are LDS + computed enc only, ZERO global loads;
//    stores contiguous aligned nt f4s.
//
// Evidence log: R1 scalar 233.7 | R2 LDS 234.2 | R3 LDS+nt 224.9 (best) |
// R4 OOB crash | R5 dual-load 236.2 | R6 shfl 231.2.
// R7 prediction: kernel ~63 -> ~52 us, dur ~212-216. If within +-4 of 224.9,
// declare structural floor next round.

typedef float f32x4 __attribute__((ext_vector_type(4)));

#define AS1 __attribute__((address_space(1)))
#define AS3 __attribute__((address_space(3)))

static constexpr unsigned kD       = 512;
static constexpr unsigned kDOut    = 517;
static constexpr unsigned kRows    = 64u * 1024u;            // 65536
static constexpr unsigned kXF4     = kRows * kD / 4u;        // 8,388,608
static constexpr unsigned kTotalF4 = kRows * kDOut / 4u;     // 8,470,528
static constexpr unsigned kThreads = 256;
static constexpr unsigned kWaves   = kThreads / 64u;         // 4
static constexpr unsigned kGroups  = kRows / 4u;             // 16384
static constexpr unsigned kBlocks  = kGroups / kWaves;       // 4096
static constexpr unsigned kImgF    = 4u * kD;                // 2048 floats / wave

static_assert(kTotalF4 == 8470528u, "out f4 count");
static_assert(kGroups * kDOut == kTotalF4, "517 out-f4 per 4-row group");
static_assert(kBlocks * kWaves == kGroups, "exact grid");

__global__ __launch_bounds__(kThreads) void pe_kernel(
    const float* __restrict__ x, float* __restrict__ out) {
  __shared__ __align__(16) float lds[kWaves * kImgF];        // 32 KB
  const unsigned t     = threadIdx.x;
  const unsigned lane  = t & 63u;
  const unsigned w     = t >> 6;
  const unsigned g     = blockIdx.x * kWaves + w;            // one group per wave
  const unsigned wbase = w * kImgF;

  // ---- stage 1: 8x global_load_lds dwordx4 -> private wave image ----
  // lane l of call k loads x-f4 (g*512 + k*64 + l); HW writes LDS at
  // (uniform base) + lane*16 -> image is the linear x-layout of rows
  // [4g, 4g+4).  max index = 16383*512 + 511 = kXF4-1: no OOB.
  const f32x4* xg = reinterpret_cast<const f32x4*>(x) + (size_t)g * (kImgF / 4u);
#pragma unroll
  for (unsigned k = 0; k < 8u; ++k) {
    __builtin_amdgcn_global_load_lds(
        (const AS1 void*)(xg + k * 64u + lane),
        (AS3 void*)(&lds[wbase + k * 256u]), 16, 0, 0);
  }
  asm volatile("s_waitcnt vmcnt(0)" ::: "memory");           // wave-local wait

  // ---- stage 2: realigned LDS reads -> aligned contiguous nt f4 stores ----
  const unsigned R0 = g * 4u;                                // first global row
  f32x4* o4 = reinterpret_cast<f32x4*>(out) + (size_t)g * kDOut;
#pragma unroll
  for (unsigned k = 0; k < 9u; ++k) {
    const unsigned j = k * 64u + lane;                       // out-f4 in group
    if (j < kDOut) {                                         // k=8: lanes 0..4
      const unsigned o  = j * 4u;                            // float in group
      const unsigned r_ = o / kDOut;                         // row 0..3
      const unsigned c  = o - r_ * kDOut;                    // col 0..516
      f32x4 v;
      if (c <= kD - 4u) {
        // fast path (509/517): 4 consecutive x floats, same row
        const unsigned xb = wbase + r_ * kD + c;
        v.x = lds[xb]; v.y = lds[xb + 1u]; v.z = lds[xb + 2u]; v.w = lds[xb + 3u];
      } else {
        // boundary (8/group): may cross row and/or hit enc cols; LDS-only
#pragma unroll
        for (unsigned e = 0; e < 4u; ++e) {
          const unsigned oo = o + e;
          const unsigned rr = oo / kDOut;
          const unsigned cc = oo - rr * kDOut;
          float val;
          if (cc < kD) {
            val = lds[wbase + rr * kD + cc];
          } else {
            const unsigned kk   = cc - kD;                   // 0..4
            const unsigned srow = (R0 + rr) & 1023u;
            const unsigned xx = srow & 31u, yy = srow >> 5, sh = 4u - kk;
            val = (float)(((xx >> sh) & 1u) & ((~(yy >> sh)) & 1u));
          }
          v[e] = val;
        }
      }
      __builtin_nontemporal_store(v, &o4[j]);
    }
  }
}

extern "C" void kernel_launch(void* const* d_in, const int* in_sizes, int n_in,
                              void* d_out, int out_size, void* d_ws,
                              size_t ws_size, hipStream_t stream) {
  const float* x = (const float*)d_in[0];
  float* out = (float*)d_out;
  // 16384 4-row groups / 4 waves per block = 4096 blocks, exact
  pe_kernel<<<dim3(kBlocks), dim3(kThreads), 0, stream>>>(x, out);
}